// Round 6
// baseline (192.896 us; speedup 1.0000x reference)
//
#include <hip/hip_runtime.h>

// GCN 2-layer, CSR-by-dst gather formulation; h1s in bf16.
// R13/R15: bucket multisplit + fused csrBG (LDS scatter, coalesced eidx).
// R14/R16 (REVERTED): per-edge global atomics / scattered global WRITES are
//      toxic on MI355X: memory-side write-through RMW + cross-XCD partial-line
//      ping-pong (R14 eidx: 106MB, R16 deg: +50MB, R17 pairs runs: +16MB).
// R18: WRITES COALESCED, READS SCATTERED. bucketAC writes each chunk SORTED
//      but CONTIGUOUS at pairs[chunkStart..] + its 512-wide exclusive-scan row
//      offmat[chunk][*]. No cursor atomics, no gpos/bb, no BKT_CAP padding.
//      csrBG finds bucket b's runs via offmat columns:
//        ebase = sum_c offmat[c][b]   (exclusive-scan identity)
//        len_c = offmat[c][b+1] - offmat[c][b]
//      and gathers the ~391 runs (scattered READS, L2-broadcast, no
//      amplification) into LDS, fusing the degree histogram. Rest = R15.
// gather1 frozen at its measured floor (~44us, L2-miss-path bound).
// out = A_hat( relu( A_hat( [x|mean]@W1 ) + b1 ) @ W2 ) + b2
// Identity: [x|mean]@W1 = x@W1[:64] + c, c = mean@W1[64:].
// Pre-scaling: h1s[s] = dis[s]*(xW1+c)[s];  h2s[s] = dis[s]*(relu(.)@W2)[s].

#define NPB        256     // nodes per bucket
#define NPB_SHIFT  8
#define BKTS       512     // split scan width (>= 391 buckets, pow2)
#define BKT_CAP    5120    // csrBG LDS staging cap (mean 4096 + 16 sigma)
#define CHUNK      4096    // edges per bucketA block
#define EPT        8       // CHUNK / 512 threads
#define CS_BLK     128     // colsum+convert blocks prepended to bucketA grid

using bf16x8 = __attribute__((ext_vector_type(8))) short;  // 8 bf16 (4 VGPRs)
using f32x4  = __attribute__((ext_vector_type(4))) float;

__device__ __forceinline__ unsigned short f2bf(float v) {
    unsigned u = __float_as_uint(v);
    u += 0x7FFFu + ((u >> 16) & 1u);   // round-to-nearest-even
    return (unsigned short)(u >> 16);
}
// two bf16 packed in a uint -> two floats (2 VALU)
__device__ __forceinline__ float bfu_lo(unsigned u) { return __uint_as_float(u << 16); }
__device__ __forceinline__ float bfu_hi(unsigned u) { return __uint_as_float(u & 0xFFFF0000u); }

// ---------- pass A: colsum+bf16cvt (0..127) + W^T->bf16 (128) + chunk sort ----------
__global__ __launch_bounds__(512) void bucketAC_kernel(
        const int* __restrict__ src, const int* __restrict__ dst,
        int e, unsigned* __restrict__ pairs, int* __restrict__ offmat,
        const float* __restrict__ x, float* __restrict__ sums,
        const float* __restrict__ W1, unsigned short* __restrict__ wtg,
        unsigned short* __restrict__ xbf, int n) {
    int tid = threadIdx.x;
    if (blockIdx.x < CS_BLK) {
        // ---- colsum side-job + bf16 conversion of x ----
        __shared__ float4 s4[512];
        int cb = blockIdx.x;
        const float4* x4 = (const float4*)x;
        int total4 = n * 16;
        float4 acc = make_float4(0.f, 0.f, 0.f, 0.f);
        for (int i = cb * 512 + tid; i < total4; i += CS_BLK * 512) {
            float4 v = x4[i];
            acc.x += v.x; acc.y += v.y; acc.z += v.z; acc.w += v.w;
            ushort4 hv;
            hv.x = f2bf(v.x); hv.y = f2bf(v.y); hv.z = f2bf(v.z); hv.w = f2bf(v.w);
            *(ushort4*)&xbf[(size_t)i * 4] = hv;
        }
        s4[tid] = acc;
        __syncthreads();
        if (tid < 16) {
            float4 v = s4[tid];
            for (int k = 1; k < 32; ++k) {
                float4 w = s4[tid + 16 * k];
                v.x += w.x; v.y += w.y; v.z += w.z; v.w += w.w;
            }
            atomicAdd(&sums[tid * 4 + 0], v.x);
            atomicAdd(&sums[tid * 4 + 1], v.y);
            atomicAdd(&sums[tid * 4 + 2], v.z);
            atomicAdd(&sums[tid * 4 + 3], v.w);
        }
        return;
    }
    if (blockIdx.x == CS_BLK) {
        // ---- W transpose side-job: wtg[j*64+k] = bf16(W1[k*64+j]), k<64 ----
        for (int i = tid; i < 4096; i += 512) {
            int k = i >> 6, j = i & 63;
            wtg[j * 64 + k] = f2bf(W1[k * 64 + j]);
        }
        return;
    }
    // ---- chunk-local bucket sort: packed 4-B records (src<<8 | dst&255) ----
    __shared__ int cnt[BKTS];
    __shared__ int wsumA[8];
    __shared__ unsigned stage[CHUNK];
    int chunkIdx = blockIdx.x - CS_BLK - 1;
    int chunkStart = chunkIdx * CHUNK;
    int v = e - chunkStart;
    if (v > CHUNK) v = CHUNK;
    cnt[tid] = 0;
    __syncthreads();
    int myb[EPT], myoff[EPT];
    unsigned myp[EPT];
#pragma unroll
    for (int t = 0; t < EPT; ++t) {
        int i = chunkStart + t * 512 + tid;
        myb[t] = -1;
        if (i < e) {
            int s = src[i], d = dst[i];
            myb[t] = d >> NPB_SHIFT;
            myp[t] = ((unsigned)s << NPB_SHIFT) | (unsigned)(d & (NPB - 1));
            myoff[t] = atomicAdd(&cnt[myb[t]], 1);
        }
    }
    __syncthreads();
    // ---- shuffle-based inclusive scan over the 512 bucket counts ----
    int lane = tid & 63, wvi = tid >> 6;
    int myCnt = cnt[tid];
    int sv = myCnt;
#pragma unroll
    for (int off = 1; off < 64; off <<= 1) {
        int t = __shfl_up(sv, off, 64);
        if (lane >= off) sv += t;
    }
    if (lane == 63) wsumA[wvi] = sv;
    __syncthreads();
    int wbase = 0;
#pragma unroll
    for (int k = 0; k < 8; ++k) if (k < wvi) wbase += wsumA[k];
    int excl = sv + wbase - myCnt;
    offmat[chunkIdx * BKTS + tid] = excl;     // coalesced 2 KB row
    cnt[tid] = excl;  // reuse as stage base
    __syncthreads();
#pragma unroll
    for (int t = 0; t < EPT; ++t) {
        if (myb[t] >= 0)
            stage[cnt[myb[t]] + myoff[t]] = myp[t];
    }
    __syncthreads();
    for (int j = tid; j < v; j += 512)
        pairs[chunkStart + j] = stage[j];     // fully coalesced, block-private
}

// ---------- pass B fused: run-gather CSR (hist+scan+fill) + cvec + MFMA gemm ----------
__global__ __launch_bounds__(512) void csrBG_kernel(
        const unsigned* __restrict__ pairs, const int* __restrict__ offmat, int nch,
        float* __restrict__ dis, int* __restrict__ rowstart,
        int* __restrict__ eidx, int n,
        const float* __restrict__ sums, const float* __restrict__ W1,
        const unsigned short* __restrict__ wtg, const unsigned short* __restrict__ xbf,
        unsigned short* __restrict__ h1s) {
    __shared__ int ldeg[NPB];       // later reused as float dis bits
    __shared__ int lcur[NPB];
    __shared__ int wred[8], wsum[8];
    __shared__ __align__(16) float cv[64];
    // union: CSR phases use pl (20KB) + el (20KB); phase-0 run tables borrow
    // el's first 6KB (dead before scatter). gemm reuses all 40KB for Ws+Xs.
    __shared__ __align__(16) char smem[BKT_CAP * 8];
    unsigned* pl = (unsigned*)smem;
    int* el    = (int*)(smem + BKT_CAP * 4);
    int* runst = el;            // [512] global start of chunk c's run
    int* plb   = el + 512;      // [512] LDS base of chunk c's run
    int* rln   = el + 1024;     // [512] run length
    unsigned short* Ws = (unsigned short*)smem;                    // 64*72
    unsigned short* Xs = (unsigned short*)(smem + 64 * 72 * 2);    // 2 tiles
    float* disl = (float*)ldeg;
    int b = blockIdx.x;
    int tid = threadIdx.x;
    int lane = tid & 63;
    int wvi = tid >> 6;
    int node0 = b << NPB_SHIFT;
    int nl = n - node0;
    if (nl > NPB) nl = NPB;
    if (tid < NPB) ldeg[tid] = 0;
    // ---- phase 0: offmat columns b, b+1 -> ebase, cnt_b, run tables ----
    int o0 = 0, len = 0;
    if (tid < nch) {
        o0 = offmat[tid * BKTS + b];
        int o1 = offmat[tid * BKTS + b + 1];     // b <= 390 < 511: always valid
        len = o1 - o0;
    }
    int c2 = o0;                                  // butterfly sum -> ebase
#pragma unroll
    for (int off = 1; off < 64; off <<= 1) c2 += __shfl_xor(c2, off, 64);
    if (lane == 0) wred[wvi] = c2;
    int svl = len;                                // ordered scan -> plb, cnt_b
#pragma unroll
    for (int off = 1; off < 64; off <<= 1) {
        int t = __shfl_up(svl, off, 64);
        if (lane >= off) svl += t;
    }
    if (lane == 63) wsum[wvi] = svl;
    __syncthreads();
    int ebase = 0, cnt_b = 0;
#pragma unroll
    for (int k = 0; k < 8; ++k) { ebase += wred[k]; cnt_b += wsum[k]; }
    int wb2 = 0;
#pragma unroll
    for (int k = 0; k < 8; ++k) if (k < wvi) wb2 += wsum[k];
    if (cnt_b > BKT_CAP) cnt_b = BKT_CAP;
    if (tid < nch) {
        runst[tid] = tid * CHUNK + o0;
        plb[tid]   = svl + wb2 - len;
        rln[tid]   = len;
    }
    __syncthreads();
    // ---- gather runs into pl (scattered READS) + fused degree histogram ----
    for (int c = wvi; c < nch; c += 8) {
        int st = runst[c], base = plb[c], L = rln[c];
        for (int k = lane; k < L; k += 64) {
            int pos = base + k;
            if (pos < BKT_CAP) {
                unsigned rec = pairs[st + k];
                pl[pos] = rec;
                atomicAdd(&ldeg[rec & (NPB - 1)], 1);
            }
        }
    }
    __syncthreads();
    // ---- shuffle-based inclusive scan of the 256 degrees ----
    int mydeg = (tid < NPB) ? ldeg[tid] : 0;
    int sv = mydeg;
#pragma unroll
    for (int off = 1; off < 64; off <<= 1) {
        int t = __shfl_up(sv, off, 64);
        if (lane >= off) sv += t;
    }
    if (lane == 63) wsum[wvi] = sv;
    __syncthreads();
    int wbase = 0;
#pragma unroll
    for (int k = 0; k < 8; ++k) if (k < wvi) wbase += wsum[k];
    int excl = sv + wbase - mydeg;
    if (tid < NPB) {
        lcur[tid] = excl;
        if (tid < nl) rowstart[node0 + tid] = ebase + excl;
        // overwrite ldeg with dis bits; all ldeg reads are before the wsum barrier
        float dv = mydeg > 0 ? rsqrtf((float)mydeg) : 0.f;
        disl[tid] = dv;
        if (tid < nl) dis[node0 + tid] = dv;
    }
    if (tid == 0 && node0 + NPB >= n)          // last bucket: close the CSR
        rowstart[n] = ebase + cnt_b;
    __syncthreads();
    // ---- scatter LDS->LDS via per-node cursors (run tables dead) ----
    for (int i = tid; i < cnt_b; i += 512) {
        unsigned p = pl[i];
        int pos = atomicAdd(&lcur[p & (NPB - 1)], 1);
        el[pos] = (int)(p >> NPB_SHIFT);
    }
    __syncthreads();
    for (int i = tid; i < cnt_b; i += 512)
        eidx[ebase + i] = el[i];               // fully coalesced
    // ---- cvec (redundant per block, trivial) ----
    if (tid < 64) {
        float inv_n = 1.0f / (float)n;
        float acc = 0.f;
        for (int k = 0; k < 64; ++k) acc += (sums[k] * inv_n) * W1[(64 + k) * 64 + tid];
        cv[tid] = acc;
    }
    __syncthreads();   // el/pl dead; smem becomes Ws/Xs
    // ---- stage W^T once ----
    for (int i = tid; i < 1024; i += 512) {
        int j = i >> 4, k4 = (i & 15) * 4;
        *(ushort4*)&Ws[j * 72 + k4] = *(const ushort4*)&wtg[j * 64 + k4];
    }
    // ---- gemm: 256 rows = 2 iters x 2 tiles x 64 rows ----
    int wv = wvi;               // 0..7
    int tile = wv >> 2;         // 0..1
    int w4 = wv & 3;            // wave within tile
    int l15 = lane & 15;
    int quad = lane >> 4;
#pragma unroll
    for (int it = 0; it < 2; ++it) {
        __syncthreads();
        // stage 128 rows (2 tiles) of pre-converted bf16 x
        for (int i = tid; i < 1024; i += 512) {
            int r = i >> 3, c8 = (i & 7) * 8;
            int gr = node0 + it * 128 + r;
            bf16x8 hv = {0, 0, 0, 0, 0, 0, 0, 0};
            if (gr < n) hv = *(const bf16x8*)&xbf[(size_t)gr * 64 + c8];
            *(bf16x8*)&Xs[((r >> 6) ? 64 * 72 : 0) + (r & 63) * 72 + c8] = hv;
        }
        __syncthreads();
        int xrow = w4 * 16 + l15;                    // row within tile
        f32x4 acc0 = {0.f, 0.f, 0.f, 0.f}, acc1 = acc0, acc2 = acc0, acc3 = acc0;
#pragma unroll
        for (int ks = 0; ks < 2; ++ks) {
            bf16x8 bfrag = *(const bf16x8*)&Xs[(tile ? 64 * 72 : 0) + xrow * 72 + ks * 32 + quad * 8];
            bf16x8 a0 = *(const bf16x8*)&Ws[(0 * 16 + l15) * 72 + ks * 32 + quad * 8];
            bf16x8 a1 = *(const bf16x8*)&Ws[(1 * 16 + l15) * 72 + ks * 32 + quad * 8];
            bf16x8 a2 = *(const bf16x8*)&Ws[(2 * 16 + l15) * 72 + ks * 32 + quad * 8];
            bf16x8 a3 = *(const bf16x8*)&Ws[(3 * 16 + l15) * 72 + ks * 32 + quad * 8];
            acc0 = __builtin_amdgcn_mfma_f32_16x16x32_bf16(a0, bfrag, acc0, 0, 0, 0);
            acc1 = __builtin_amdgcn_mfma_f32_16x16x32_bf16(a1, bfrag, acc1, 0, 0, 0);
            acc2 = __builtin_amdgcn_mfma_f32_16x16x32_bf16(a2, bfrag, acc2, 0, 0, 0);
            acc3 = __builtin_amdgcn_mfma_f32_16x16x32_bf16(a3, bfrag, acc3, 0, 0, 0);
        }
        int lrow = it * 128 + tile * 64 + xrow;      // row within bucket
        int grow = node0 + lrow;
        if (grow < n) {
            float dv = disl[lrow];
            const float4* c4 = (const float4*)cv;
            f32x4 accs[4] = {acc0, acc1, acc2, acc3};
#pragma unroll
            for (int t = 0; t < 4; ++t) {
                float4 cj = c4[t * 4 + quad];
                ushort4 hs;
                hs.x = f2bf((accs[t][0] + cj.x) * dv);
                hs.y = f2bf((accs[t][1] + cj.y) * dv);
                hs.z = f2bf((accs[t][2] + cj.z) * dv);
                hs.w = f2bf((accs[t][3] + cj.w) * dv);
                *(ushort4*)&h1s[(size_t)grow * 64 + t * 16 + quad * 4] = hs;
            }
        }
    }
}

// ---------- layer-1 gather: 32 lanes/edge (ushort2/lane), 8 loads in flight ----------
__global__ void gather1_kernel(const int* __restrict__ rowstart,
                               const int* __restrict__ eidx, const float* __restrict__ dis,
                               const unsigned short* __restrict__ h1s,
                               const float* __restrict__ b1, const float* __restrict__ W2,
                               float* __restrict__ h2s, int n) {
    int lane = threadIdx.x & 63;
    int node = blockIdx.x * 4 + (threadIdx.x >> 6);
    if (node >= n) return;
    int rs = rowstart[node];
    int re = rowstart[node + 1];
    int dn = re - rs;
    int m = dn < 64 ? dn : 64;
    int eHeld = (lane < m) ? eidx[rs + lane] : 0;  // one coalesced load for <=64 edges
    int sub = lane >> 5;        // edge subgroup 0..1
    int fp  = (lane & 31) * 2;  // feature pair base
    float ax = 0.f, ay = 0.f;
    int j = 0;
    for (; j + 16 <= m; j += 16) {        // 16 edges per iter, 8 loads in flight
        int s0 = __shfl(eHeld, j + 0 + sub, 64);
        int s1 = __shfl(eHeld, j + 2 + sub, 64);
        int s2 = __shfl(eHeld, j + 4 + sub, 64);
        int s3 = __shfl(eHeld, j + 6 + sub, 64);
        int s4 = __shfl(eHeld, j + 8 + sub, 64);
        int s5 = __shfl(eHeld, j + 10 + sub, 64);
        int s6 = __shfl(eHeld, j + 12 + sub, 64);
        int s7 = __shfl(eHeld, j + 14 + sub, 64);
        unsigned u0 = *(const unsigned*)&h1s[((size_t)s0 << 6) + fp];
        unsigned u1 = *(const unsigned*)&h1s[((size_t)s1 << 6) + fp];
        unsigned u2 = *(const unsigned*)&h1s[((size_t)s2 << 6) + fp];
        unsigned u3 = *(const unsigned*)&h1s[((size_t)s3 << 6) + fp];
        unsigned u4 = *(const unsigned*)&h1s[((size_t)s4 << 6) + fp];
        unsigned u5 = *(const unsigned*)&h1s[((size_t)s5 << 6) + fp];
        unsigned u6 = *(const unsigned*)&h1s[((size_t)s6 << 6) + fp];
        unsigned u7 = *(const unsigned*)&h1s[((size_t)s7 << 6) + fp];
        ax += (bfu_lo(u0) + bfu_lo(u1)) + (bfu_lo(u2) + bfu_lo(u3))
            + (bfu_lo(u4) + bfu_lo(u5)) + (bfu_lo(u6) + bfu_lo(u7));
        ay += (bfu_hi(u0) + bfu_hi(u1)) + (bfu_hi(u2) + bfu_hi(u3))
            + (bfu_hi(u4) + bfu_hi(u5)) + (bfu_hi(u6) + bfu_hi(u7));
    }
    for (; j + 8 <= m; j += 8) {          // 8-edge tail, 4 loads
        int s0 = __shfl(eHeld, j + 0 + sub, 64);
        int s1 = __shfl(eHeld, j + 2 + sub, 64);
        int s2 = __shfl(eHeld, j + 4 + sub, 64);
        int s3 = __shfl(eHeld, j + 6 + sub, 64);
        unsigned u0 = *(const unsigned*)&h1s[((size_t)s0 << 6) + fp];
        unsigned u1 = *(const unsigned*)&h1s[((size_t)s1 << 6) + fp];
        unsigned u2 = *(const unsigned*)&h1s[((size_t)s2 << 6) + fp];
        unsigned u3 = *(const unsigned*)&h1s[((size_t)s3 << 6) + fp];
        ax += (bfu_lo(u0) + bfu_lo(u1)) + (bfu_lo(u2) + bfu_lo(u3));
        ay += (bfu_hi(u0) + bfu_hi(u1)) + (bfu_hi(u2) + bfu_hi(u3));
    }
    for (; j + 4 <= m; j += 4) {          // 4-edge tail, 2 loads
        int s0 = __shfl(eHeld, j + 0 + sub, 64);
        int s1 = __shfl(eHeld, j + 2 + sub, 64);
        unsigned u0 = *(const unsigned*)&h1s[((size_t)s0 << 6) + fp];
        unsigned u1 = *(const unsigned*)&h1s[((size_t)s1 << 6) + fp];
        ax += bfu_lo(u0) + bfu_lo(u1);
        ay += bfu_hi(u0) + bfu_hi(u1);
    }
    for (; j < m; j += 2) {               // ragged tail (0..1 edges per sub)
        int jj = j + sub;
        int s = __shfl(eHeld, jj < m ? jj : 0, 64);
        if (jj < m) {
            unsigned u = *(const unsigned*)&h1s[((size_t)s << 6) + fp];
            ax += bfu_lo(u);
            ay += bfu_hi(u);
        }
    }
    for (int t = 64; t < dn; ++t) {       // deg > 64: astronomically rare here
        if (sub == 0) {
            int s = eidx[rs + t];
            unsigned u = *(const unsigned*)&h1s[((size_t)s << 6) + fp];
            ax += bfu_lo(u);
            ay += bfu_hi(u);
        }
    }
    // reduce across the 2 edge subgroups (both halves end with full sums)
    ax += __shfl_xor(ax, 32, 64);
    ay += __shfl_xor(ay, 32, 64);
    float di = dis[node];
    float2 bv = ((const float2*)b1)[lane & 31];
    float4 w = ((const float4*)W2)[lane & 31];   // W2[fp][0..1], W2[fp+1][0..1]
    float t0 = fmaxf(di * ax + bv.x, 0.f);
    float t1 = fmaxf(di * ay + bv.y, 0.f);
    float v0 = t0 * w.x + t1 * w.z;
    float v1 = t0 * w.y + t1 * w.w;
#pragma unroll
    for (int off = 1; off <= 16; off <<= 1) {   // sum the 32 feature classes
        v0 += __shfl_xor(v0, off, 64);
        v1 += __shfl_xor(v1, off, 64);
    }
    if (lane == 0) {
        h2s[(size_t)node * 2 + 0] = di * v0;
        h2s[(size_t)node * 2 + 1] = di * v1;
    }
}

// ---------- layer-2 gather: 16 lanes per node, one lane per edge ----------
__global__ void gather2_kernel(const int* __restrict__ rowstart,
                               const int* __restrict__ eidx, const float* __restrict__ dis,
                               const float2* __restrict__ h2s, const float* __restrict__ b2,
                               float2* __restrict__ out, int n) {
    int tid = threadIdx.x;
    int node = blockIdx.x * 16 + (tid >> 4);
    if (node >= n) return;
    int el = tid & 15;
    int rs = rowstart[node];
    int dn = rowstart[node + 1] - rs;
    float ax = 0.f, ay = 0.f;
    for (int t = el; t < dn; t += 16) {   // 16 edges in flight per node
        int s = eidx[rs + t];
        float2 h = h2s[s];
        ax += h.x;
        ay += h.y;
    }
#pragma unroll
    for (int off = 1; off <= 8; off <<= 1) {
        ax += __shfl_xor(ax, off, 64);
        ay += __shfl_xor(ay, off, 64);
    }
    if (el == 0) {
        float di = dis[node];
        out[node] = make_float2(di * ax + b2[0], di * ay + b2[1]);
    }
}

extern "C" void kernel_launch(void* const* d_in, const int* in_sizes, int n_in,
                              void* d_out, int out_size, void* d_ws, size_t ws_size,
                              hipStream_t stream) {
    const float* x  = (const float*)d_in[0];
    const int*   ei = (const int*)d_in[1];
    const float* W1 = (const float*)d_in[2];
    const float* b1 = (const float*)d_in[3];
    const float* W2 = (const float*)d_in[4];
    const float* b2 = (const float*)d_in[5];
    float2* out = (float2*)d_out;

    const int n = in_sizes[0] / 64;   // 100000
    const int e = in_sizes[1] / 2;    // 1600000
    const int* srcI = ei;
    const int* dstI = ei + e;
    const int nbkt = (n + NPB - 1) >> NPB_SHIFT;   // 391
    const int nch  = (e + CHUNK - 1) / CHUNK;      // 391 (must be <= 512)

    // workspace layout (256-B aligned segments)
    char* p = (char*)d_ws;
    int* rowstart = (int*)p;    p += ((size_t)(n + 1) * 4 + 255) & ~255ull;
    float* dis    = (float*)p;  p += ((size_t)n * 4 + 255) & ~255ull;
    float* sums   = (float*)p;  p += 256;          // only thing memset
    int* offmat   = (int*)p;    p += ((size_t)nch * BKTS * 4 + 255) & ~255ull;
    unsigned short* wtg = (unsigned short*)p;  p += (4096 * 2 + 255) & ~255ull;
    unsigned short* xbf = (unsigned short*)p;  p += ((size_t)n * 64 * 2 + 255) & ~255ull;
    int* eidx     = (int*)p;    p += ((size_t)e * 4 + 255) & ~255ull;
    unsigned* pairs = (unsigned*)p;  p += ((size_t)e * 4 + 255) & ~255ull;   // exact size
    unsigned short* h1s = (unsigned short*)p;  p += ((size_t)n * 64 * 2 + 255) & ~255ull;
    float* h2s    = (float*)p;

    hipMemsetAsync(sums, 0, 256, stream);

    bucketAC_kernel<<<CS_BLK + 1 + nch, 512, 0, stream>>>(srcI, dstI, e, pairs, offmat,
                                                          x, sums, W1, wtg, xbf, n);
    csrBG_kernel<<<nbkt, 512, 0, stream>>>(pairs, offmat, nch, dis, rowstart, eidx, n,
                                           sums, W1, wtg, xbf, h1s);
    gather1_kernel<<<(n + 3) / 4, 256, 0, stream>>>(rowstart, eidx, dis, h1s, b1, W2, h2s, n);
    gather2_kernel<<<(n + 15) / 16, 256, 0, stream>>>(rowstart, eidx, dis, (const float2*)h2s,
                                                      b2, out, n);
}

// Round 8
// 175.450 us; speedup vs baseline: 1.0994x; 1.0994x over previous
//
#include <hip/hip_runtime.h>

// GCN 2-layer, CSR-by-dst gather formulation; h1s in bf16.
// R15 (BEST, 173.2us): bucket multisplit CHUNK=8192 + fused csrBG
//      (pairs staged to LDS once, LDS scatter, coalesced eidx writeout).
// REVERTED experiments (keep for the record):
//   R14/R16: per-edge global atomics are toxic on MI355X (memory-side
//      write-through RMW ~32B/op + cross-XCD partial-line ping-pong).
//      eidx scatter: 106MB writes; deg hist: +50MB writes.
//   R17: CHUNK=2048 (more TLP) -> pairs runs too short, WRITE 35MB (+16MB
//      amplification), bucketAC 46-48us. CHUNK=8192 is the sweet spot.
//   R18: coalesced-write chunks + csrBG run-gather -> 391 short scattered
//      run-reads per block, ~10/64 lanes active, lost ~20us.
// R19: R15 exact, plus csrBG-only overlap (from R17, never implicated):
//      cvec at entry (global loads overlap LDS phases); Ws staged during
//      eidx writeout (pl dead; el untouched until barrier).
//      (R7 bench attempt hit an infra failure; resubmitted unchanged.)
// gather1 frozen at its measured floor (~44us, L2/L3-miss-path bound).
// out = A_hat( relu( A_hat( [x|mean]@W1 ) + b1 ) @ W2 ) + b2
// Identity: [x|mean]@W1 = x@W1[:64] + c, c = mean@W1[64:].
// Pre-scaling: h1s[s] = dis[s]*(xW1+c)[s];  h2s[s] = dis[s]*(relu(.)@W2)[s].

#define NPB        256     // nodes per bucket
#define NPB_SHIFT  8
#define BKTS       512     // scan width (>= 391 buckets, pow2)
#define BKT_CAP    5120    // mean 4096 + 16 sigma
#define CHUNK      8192    // edges per bucketA block
#define EPT        16      // CHUNK / 512 threads
#define CS_BLK     128     // colsum+convert blocks prepended to bucketA grid
#define CUR_STRIDE 32      // ints per cursor slot (128-B line each)

using bf16x8 = __attribute__((ext_vector_type(8))) short;  // 8 bf16 (4 VGPRs)
using f32x4  = __attribute__((ext_vector_type(4))) float;

__device__ __forceinline__ unsigned short f2bf(float v) {
    unsigned u = __float_as_uint(v);
    u += 0x7FFFu + ((u >> 16) & 1u);   // round-to-nearest-even
    return (unsigned short)(u >> 16);
}
// two bf16 packed in a uint -> two floats (2 VALU)
__device__ __forceinline__ float bfu_lo(unsigned u) { return __uint_as_float(u << 16); }
__device__ __forceinline__ float bfu_hi(unsigned u) { return __uint_as_float(u & 0xFFFF0000u); }

// ---------- pass A: colsum+bf16cvt (0..127) + W^T->bf16 (128) + multi-split ----------
__global__ __launch_bounds__(512) void bucketAC_kernel(
        const int* __restrict__ src, const int* __restrict__ dst,
        int e, unsigned* __restrict__ pairs, int* __restrict__ cursor,
        const float* __restrict__ x, float* __restrict__ sums,
        const float* __restrict__ W1, unsigned short* __restrict__ wtg,
        unsigned short* __restrict__ xbf, int n) {
    int tid = threadIdx.x;
    if (blockIdx.x < CS_BLK) {
        // ---- colsum side-job + bf16 conversion of x ----
        __shared__ float4 s4[512];
        int cb = blockIdx.x;
        const float4* x4 = (const float4*)x;
        int total4 = n * 16;
        float4 acc = make_float4(0.f, 0.f, 0.f, 0.f);
        for (int i = cb * 512 + tid; i < total4; i += CS_BLK * 512) {
            float4 v = x4[i];
            acc.x += v.x; acc.y += v.y; acc.z += v.z; acc.w += v.w;
            ushort4 hv;
            hv.x = f2bf(v.x); hv.y = f2bf(v.y); hv.z = f2bf(v.z); hv.w = f2bf(v.w);
            *(ushort4*)&xbf[(size_t)i * 4] = hv;
        }
        s4[tid] = acc;
        __syncthreads();
        if (tid < 16) {
            float4 v = s4[tid];
            for (int k = 1; k < 32; ++k) {
                float4 w = s4[tid + 16 * k];
                v.x += w.x; v.y += w.y; v.z += w.z; v.w += w.w;
            }
            atomicAdd(&sums[tid * 4 + 0], v.x);
            atomicAdd(&sums[tid * 4 + 1], v.y);
            atomicAdd(&sums[tid * 4 + 2], v.z);
            atomicAdd(&sums[tid * 4 + 3], v.w);
        }
        return;
    }
    if (blockIdx.x == CS_BLK) {
        // ---- W transpose side-job: wtg[j*64+k] = bf16(W1[k*64+j]), k<64 ----
        for (int i = tid; i < 4096; i += 512) {
            int k = i >> 6, j = i & 63;
            wtg[j * 64 + k] = f2bf(W1[k * 64 + j]);
        }
        return;
    }
    // ---- bucket multi-split: packed 4-B records (src<<8 | dst&255) ----
    __shared__ int cnt[BKTS], gpos[BKTS];
    __shared__ int wsumA[8];
    __shared__ unsigned stage[CHUNK];
    __shared__ unsigned short bb[CHUNK];
    int chunkStart = (blockIdx.x - CS_BLK - 1) * CHUNK;
    int v = e - chunkStart;
    if (v > CHUNK) v = CHUNK;
    cnt[tid] = 0;
    __syncthreads();
    int myb[EPT], myoff[EPT];
    unsigned myp[EPT];
#pragma unroll
    for (int t = 0; t < EPT; ++t) {
        int i = chunkStart + t * 512 + tid;
        myb[t] = -1;
        if (i < e) {
            int s = src[i], d = dst[i];
            myb[t] = d >> NPB_SHIFT;
            myp[t] = ((unsigned)s << NPB_SHIFT) | (unsigned)(d & (NPB - 1));
            myoff[t] = atomicAdd(&cnt[myb[t]], 1);
        }
    }
    __syncthreads();
    // ---- shuffle-based inclusive scan over the 512 bucket counts ----
    int lane = tid & 63, wvi = tid >> 6;
    int myCnt = cnt[tid];
    int sv = myCnt;
#pragma unroll
    for (int off = 1; off < 64; off <<= 1) {
        int t = __shfl_up(sv, off, 64);
        if (lane >= off) sv += t;
    }
    if (lane == 63) wsumA[wvi] = sv;
    __syncthreads();
    int wbase = 0;
#pragma unroll
    for (int k = 0; k < 8; ++k) if (k < wvi) wbase += wsumA[k];
    int excl = sv + wbase - myCnt;
    if (myCnt > 0) {
        int gb = atomicAdd(&cursor[tid * CUR_STRIDE], myCnt);  // private line
        gpos[tid] = tid * BKT_CAP + gb - excl;
    }
    cnt[tid] = excl;  // reuse as stage base
    __syncthreads();
#pragma unroll
    for (int t = 0; t < EPT; ++t) {
        if (myb[t] >= 0) {
            int p = cnt[myb[t]] + myoff[t];
            stage[p] = myp[t];
            bb[p] = (unsigned short)myb[t];
        }
    }
    __syncthreads();
    for (int j = tid; j < v; j += 512) {
        int bk = bb[j];
        int wi = gpos[bk] + j;
        if (wi < (bk + 1) * BKT_CAP) pairs[wi] = stage[j];  // contiguous runs
    }
}

// ---------- pass B fused: CSR (LDS-staged hist+scan+fill) + cvec + MFMA gemm ----------
__global__ __launch_bounds__(512) void csrBG_kernel(
        const unsigned* __restrict__ pairs, const int* __restrict__ cursor,
        float* __restrict__ dis, int* __restrict__ rowstart,
        int* __restrict__ eidx, int n,
        const float* __restrict__ sums, const float* __restrict__ W1,
        const unsigned short* __restrict__ wtg, const unsigned short* __restrict__ xbf,
        unsigned short* __restrict__ h1s) {
    __shared__ int ldeg[NPB];       // later reused as float dis bits
    __shared__ int lcur[NPB];
    __shared__ int wred[8], wsum[8];
    __shared__ __align__(16) float cv[64];
    // union: phases 1-3 use pl (pairs local, 20KB) + el (eidx local, 20KB);
    // gemm phase reuses the same 40KB for Ws (9KB, 0..9216) + Xs (18.4KB,
    // 9216..27648). Ws staging overlaps eidx writeout: Ws region = dead pl;
    // el (20480..) is only read until the post-writeout barrier.
    __shared__ __align__(16) char smem[BKT_CAP * 8];
    unsigned* pl = (unsigned*)smem;
    int* el = (int*)(smem + BKT_CAP * 4);
    unsigned short* Ws = (unsigned short*)smem;                    // 64*72
    unsigned short* Xs = (unsigned short*)(smem + 64 * 72 * 2);    // 2 tiles
    float* disl = (float*)ldeg;
    int b = blockIdx.x;
    int tid = threadIdx.x;
    int lane = tid & 63;
    int wvi = tid >> 6;
    int node0 = b << NPB_SHIFT;
    int nl = n - node0;
    if (nl > NPB) nl = NPB;
    int cnt_b = cursor[b * CUR_STRIDE];
    if (cnt_b > BKT_CAP) cnt_b = BKT_CAP;
    if (tid < NPB) ldeg[tid] = 0;
    // ---- cvec hoisted: independent global loads overlap the LDS phases ----
    if (tid < 64) {
        float inv_n = 1.0f / (float)n;
        float acc = 0.f;
        for (int k = 0; k < 64; ++k) acc += (sums[k] * inv_n) * W1[(64 + k) * 64 + tid];
        cv[tid] = acc;
    }
    // ---- ebase = sum of earlier buckets' counts, via shuffle reduction ----
    int c = (tid < b) ? cursor[tid * CUR_STRIDE] : 0;
#pragma unroll
    for (int off = 1; off < 64; off <<= 1) c += __shfl_xor(c, off, 64);
    if (lane == 0) wred[wvi] = c;
    __syncthreads();
    // ---- stage pairs to LDS + histogram in ONE pass (global read once) ----
    const unsigned* mp = pairs + (size_t)b * BKT_CAP;
    for (int i = tid; i < cnt_b; i += 512) {
        unsigned p = mp[i];
        pl[i] = p;
        atomicAdd(&ldeg[p & (NPB - 1)], 1);
    }
    int ebase = 0;
#pragma unroll
    for (int k = 0; k < 8; ++k) ebase += wred[k];
    __syncthreads();
    // ---- shuffle-based inclusive scan of the 256 degrees ----
    int mydeg = (tid < NPB) ? ldeg[tid] : 0;
    int sv = mydeg;
#pragma unroll
    for (int off = 1; off < 64; off <<= 1) {
        int t = __shfl_up(sv, off, 64);
        if (lane >= off) sv += t;
    }
    if (lane == 63) wsum[wvi] = sv;
    __syncthreads();
    int wbase = 0;
#pragma unroll
    for (int k = 0; k < 8; ++k) if (k < wvi) wbase += wsum[k];
    int excl = sv + wbase - mydeg;
    if (tid < NPB) {
        lcur[tid] = excl;
        if (tid < nl) rowstart[node0 + tid] = ebase + excl;
        // overwrite ldeg with dis bits; all ldeg reads are before the wsum barrier
        float dv = mydeg > 0 ? rsqrtf((float)mydeg) : 0.f;
        disl[tid] = dv;
        if (tid < nl) dis[node0 + tid] = dv;
    }
    if (tid == 0 && node0 + NPB >= n)          // last bucket: close the CSR
        rowstart[n] = ebase + cnt_b;
    __syncthreads();
    // ---- scatter LDS->LDS via per-node cursors ----
    for (int i = tid; i < cnt_b; i += 512) {
        unsigned p = pl[i];
        int pos = atomicAdd(&lcur[p & (NPB - 1)], 1);
        el[pos] = (int)(p >> NPB_SHIFT);
    }
    __syncthreads();
    // ---- Ws staging (pl region dead) overlaps the coalesced eidx writeout ----
    for (int i = tid; i < 1024; i += 512) {
        int j = i >> 4, k4 = (i & 15) * 4;
        *(ushort4*)&Ws[j * 72 + k4] = *(const ushort4*)&wtg[j * 64 + k4];
    }
    for (int i = tid; i < cnt_b; i += 512)
        eidx[ebase + i] = el[i];               // fully coalesced
    __syncthreads();   // el dead; Xs region free
    // ---- gemm: 256 rows = 2 iters x 2 tiles x 64 rows ----
    int wv = wvi;               // 0..7
    int tile = wv >> 2;         // 0..1
    int w4 = wv & 3;            // wave within tile
    int l15 = lane & 15;
    int quad = lane >> 4;
#pragma unroll
    for (int it = 0; it < 2; ++it) {
        // stage 128 rows (2 tiles) of pre-converted bf16 x
        for (int i = tid; i < 1024; i += 512) {
            int r = i >> 3, c8 = (i & 7) * 8;
            int gr = node0 + it * 128 + r;
            bf16x8 hv = {0, 0, 0, 0, 0, 0, 0, 0};
            if (gr < n) hv = *(const bf16x8*)&xbf[(size_t)gr * 64 + c8];
            *(bf16x8*)&Xs[((r >> 6) ? 64 * 72 : 0) + (r & 63) * 72 + c8] = hv;
        }
        __syncthreads();
        int xrow = w4 * 16 + l15;                    // row within tile
        f32x4 acc0 = {0.f, 0.f, 0.f, 0.f}, acc1 = acc0, acc2 = acc0, acc3 = acc0;
#pragma unroll
        for (int ks = 0; ks < 2; ++ks) {
            bf16x8 bfrag = *(const bf16x8*)&Xs[(tile ? 64 * 72 : 0) + xrow * 72 + ks * 32 + quad * 8];
            bf16x8 a0 = *(const bf16x8*)&Ws[(0 * 16 + l15) * 72 + ks * 32 + quad * 8];
            bf16x8 a1 = *(const bf16x8*)&Ws[(1 * 16 + l15) * 72 + ks * 32 + quad * 8];
            bf16x8 a2 = *(const bf16x8*)&Ws[(2 * 16 + l15) * 72 + ks * 32 + quad * 8];
            bf16x8 a3 = *(const bf16x8*)&Ws[(3 * 16 + l15) * 72 + ks * 32 + quad * 8];
            acc0 = __builtin_amdgcn_mfma_f32_16x16x32_bf16(a0, bfrag, acc0, 0, 0, 0);
            acc1 = __builtin_amdgcn_mfma_f32_16x16x32_bf16(a1, bfrag, acc1, 0, 0, 0);
            acc2 = __builtin_amdgcn_mfma_f32_16x16x32_bf16(a2, bfrag, acc2, 0, 0, 0);
            acc3 = __builtin_amdgcn_mfma_f32_16x16x32_bf16(a3, bfrag, acc3, 0, 0, 0);
        }
        int lrow = it * 128 + tile * 64 + xrow;      // row within bucket
        int grow = node0 + lrow;
        if (grow < n) {
            float dv = disl[lrow];
            const float4* c4 = (const float4*)cv;
            f32x4 accs[4] = {acc0, acc1, acc2, acc3};
#pragma unroll
            for (int t = 0; t < 4; ++t) {
                float4 cj = c4[t * 4 + quad];
                ushort4 hs;
                hs.x = f2bf((accs[t][0] + cj.x) * dv);
                hs.y = f2bf((accs[t][1] + cj.y) * dv);
                hs.z = f2bf((accs[t][2] + cj.z) * dv);
                hs.w = f2bf((accs[t][3] + cj.w) * dv);
                *(ushort4*)&h1s[(size_t)grow * 64 + t * 16 + quad * 4] = hs;
            }
        }
        if (it == 0) __syncthreads();   // protect Xs before restage
    }
}

// ---------- layer-1 gather: 32 lanes/edge (ushort2/lane), 8 loads in flight ----------
__global__ void gather1_kernel(const int* __restrict__ rowstart,
                               const int* __restrict__ eidx, const float* __restrict__ dis,
                               const unsigned short* __restrict__ h1s,
                               const float* __restrict__ b1, const float* __restrict__ W2,
                               float* __restrict__ h2s, int n) {
    int lane = threadIdx.x & 63;
    int node = blockIdx.x * 4 + (threadIdx.x >> 6);
    if (node >= n) return;
    int rs = rowstart[node];
    int re = rowstart[node + 1];
    int dn = re - rs;
    int m = dn < 64 ? dn : 64;
    int eHeld = (lane < m) ? eidx[rs + lane] : 0;  // one coalesced load for <=64 edges
    int sub = lane >> 5;        // edge subgroup 0..1
    int fp  = (lane & 31) * 2;  // feature pair base
    float ax = 0.f, ay = 0.f;
    int j = 0;
    for (; j + 16 <= m; j += 16) {        // 16 edges per iter, 8 loads in flight
        int s0 = __shfl(eHeld, j + 0 + sub, 64);
        int s1 = __shfl(eHeld, j + 2 + sub, 64);
        int s2 = __shfl(eHeld, j + 4 + sub, 64);
        int s3 = __shfl(eHeld, j + 6 + sub, 64);
        int s4 = __shfl(eHeld, j + 8 + sub, 64);
        int s5 = __shfl(eHeld, j + 10 + sub, 64);
        int s6 = __shfl(eHeld, j + 12 + sub, 64);
        int s7 = __shfl(eHeld, j + 14 + sub, 64);
        unsigned u0 = *(const unsigned*)&h1s[((size_t)s0 << 6) + fp];
        unsigned u1 = *(const unsigned*)&h1s[((size_t)s1 << 6) + fp];
        unsigned u2 = *(const unsigned*)&h1s[((size_t)s2 << 6) + fp];
        unsigned u3 = *(const unsigned*)&h1s[((size_t)s3 << 6) + fp];
        unsigned u4 = *(const unsigned*)&h1s[((size_t)s4 << 6) + fp];
        unsigned u5 = *(const unsigned*)&h1s[((size_t)s5 << 6) + fp];
        unsigned u6 = *(const unsigned*)&h1s[((size_t)s6 << 6) + fp];
        unsigned u7 = *(const unsigned*)&h1s[((size_t)s7 << 6) + fp];
        ax += (bfu_lo(u0) + bfu_lo(u1)) + (bfu_lo(u2) + bfu_lo(u3))
            + (bfu_lo(u4) + bfu_lo(u5)) + (bfu_lo(u6) + bfu_lo(u7));
        ay += (bfu_hi(u0) + bfu_hi(u1)) + (bfu_hi(u2) + bfu_hi(u3))
            + (bfu_hi(u4) + bfu_hi(u5)) + (bfu_hi(u6) + bfu_hi(u7));
    }
    for (; j + 8 <= m; j += 8) {          // 8-edge tail, 4 loads
        int s0 = __shfl(eHeld, j + 0 + sub, 64);
        int s1 = __shfl(eHeld, j + 2 + sub, 64);
        int s2 = __shfl(eHeld, j + 4 + sub, 64);
        int s3 = __shfl(eHeld, j + 6 + sub, 64);
        unsigned u0 = *(const unsigned*)&h1s[((size_t)s0 << 6) + fp];
        unsigned u1 = *(const unsigned*)&h1s[((size_t)s1 << 6) + fp];
        unsigned u2 = *(const unsigned*)&h1s[((size_t)s2 << 6) + fp];
        unsigned u3 = *(const unsigned*)&h1s[((size_t)s3 << 6) + fp];
        ax += (bfu_lo(u0) + bfu_lo(u1)) + (bfu_lo(u2) + bfu_lo(u3));
        ay += (bfu_hi(u0) + bfu_hi(u1)) + (bfu_hi(u2) + bfu_hi(u3));
    }
    for (; j + 4 <= m; j += 4) {          // 4-edge tail, 2 loads
        int s0 = __shfl(eHeld, j + 0 + sub, 64);
        int s1 = __shfl(eHeld, j + 2 + sub, 64);
        unsigned u0 = *(const unsigned*)&h1s[((size_t)s0 << 6) + fp];
        unsigned u1 = *(const unsigned*)&h1s[((size_t)s1 << 6) + fp];
        ax += bfu_lo(u0) + bfu_lo(u1);
        ay += bfu_hi(u0) + bfu_hi(u1);
    }
    for (; j < m; j += 2) {               // ragged tail (0..1 edges per sub)
        int jj = j + sub;
        int s = __shfl(eHeld, jj < m ? jj : 0, 64);
        if (jj < m) {
            unsigned u = *(const unsigned*)&h1s[((size_t)s << 6) + fp];
            ax += bfu_lo(u);
            ay += bfu_hi(u);
        }
    }
    for (int t = 64; t < dn; ++t) {       // deg > 64: astronomically rare here
        if (sub == 0) {
            int s = eidx[rs + t];
            unsigned u = *(const unsigned*)&h1s[((size_t)s << 6) + fp];
            ax += bfu_lo(u);
            ay += bfu_hi(u);
        }
    }
    // reduce across the 2 edge subgroups (both halves end with full sums)
    ax += __shfl_xor(ax, 32, 64);
    ay += __shfl_xor(ay, 32, 64);
    float di = dis[node];
    float2 bv = ((const float2*)b1)[lane & 31];
    float4 w = ((const float4*)W2)[lane & 31];   // W2[fp][0..1], W2[fp+1][0..1]
    float t0 = fmaxf(di * ax + bv.x, 0.f);
    float t1 = fmaxf(di * ay + bv.y, 0.f);
    float v0 = t0 * w.x + t1 * w.z;
    float v1 = t0 * w.y + t1 * w.w;
#pragma unroll
    for (int off = 1; off <= 16; off <<= 1) {   // sum the 32 feature classes
        v0 += __shfl_xor(v0, off, 64);
        v1 += __shfl_xor(v1, off, 64);
    }
    if (lane == 0) {
        h2s[(size_t)node * 2 + 0] = di * v0;
        h2s[(size_t)node * 2 + 1] = di * v1;
    }
}

// ---------- layer-2 gather: 16 lanes per node, one lane per edge ----------
__global__ void gather2_kernel(const int* __restrict__ rowstart,
                               const int* __restrict__ eidx, const float* __restrict__ dis,
                               const float2* __restrict__ h2s, const float* __restrict__ b2,
                               float2* __restrict__ out, int n) {
    int tid = threadIdx.x;
    int node = blockIdx.x * 16 + (tid >> 4);
    if (node >= n) return;
    int el = tid & 15;
    int rs = rowstart[node];
    int dn = rowstart[node + 1] - rs;
    float ax = 0.f, ay = 0.f;
    for (int t = el; t < dn; t += 16) {   // 16 edges in flight per node
        int s = eidx[rs + t];
        float2 h = h2s[s];
        ax += h.x;
        ay += h.y;
    }
#pragma unroll
    for (int off = 1; off <= 8; off <<= 1) {
        ax += __shfl_xor(ax, off, 64);
        ay += __shfl_xor(ay, off, 64);
    }
    if (el == 0) {
        float di = dis[node];
        out[node] = make_float2(di * ax + b2[0], di * ay + b2[1]);
    }
}

extern "C" void kernel_launch(void* const* d_in, const int* in_sizes, int n_in,
                              void* d_out, int out_size, void* d_ws, size_t ws_size,
                              hipStream_t stream) {
    const float* x  = (const float*)d_in[0];
    const int*   ei = (const int*)d_in[1];
    const float* W1 = (const float*)d_in[2];
    const float* b1 = (const float*)d_in[3];
    const float* W2 = (const float*)d_in[4];
    const float* b2 = (const float*)d_in[5];
    float2* out = (float2*)d_out;

    const int n = in_sizes[0] / 64;   // 100000
    const int e = in_sizes[1] / 2;    // 1600000
    const int* srcI = ei;
    const int* dstI = ei + e;
    const int nbkt = (n + NPB - 1) >> NPB_SHIFT;   // 391

    // workspace layout (256-B aligned segments); sums+cursor adjacent -> 1 memset
    char* p = (char*)d_ws;
    int* rowstart = (int*)p;    p += ((size_t)(n + 1) * 4 + 255) & ~255ull;
    float* dis    = (float*)p;  p += ((size_t)n * 4 + 255) & ~255ull;
    float* sums   = (float*)p;                  // 256 B
    int* cursor   = (int*)(p + 256);            // nbkt * 128-B padded slots
    size_t zsize  = 256 + (size_t)nbkt * CUR_STRIDE * 4;
    char* zbase   = p;          p += (zsize + 255) & ~255ull;
    unsigned short* wtg = (unsigned short*)p;  p += (4096 * 2 + 255) & ~255ull;
    unsigned short* xbf = (unsigned short*)p;  p += ((size_t)n * 64 * 2 + 255) & ~255ull;
    int* eidx     = (int*)p;    p += ((size_t)e * 4 + 255) & ~255ull;
    // keep pairs and h1s in SEPARATE regions (no union) - ws is large enough.
    unsigned* pairs = (unsigned*)p;  p += ((size_t)nbkt * BKT_CAP * 4 + 255) & ~255ull;
    unsigned short* h1s = (unsigned short*)p;  p += ((size_t)n * 64 * 2 + 255) & ~255ull;
    float* h2s    = (float*)p;

    hipMemsetAsync(zbase, 0, zsize, stream);

    const int nchunks = (e + CHUNK - 1) / CHUNK;           // 196

    bucketAC_kernel<<<CS_BLK + 1 + nchunks, 512, 0, stream>>>(srcI, dstI, e, pairs, cursor,
                                                              x, sums, W1, wtg, xbf, n);
    csrBG_kernel<<<nbkt, 512, 0, stream>>>(pairs, cursor, dis, rowstart, eidx, n,
                                           sums, W1, wtg, xbf, h1s);
    gather1_kernel<<<(n + 3) / 4, 256, 0, stream>>>(rowstart, eidx, dis, h1s, b1, W2, h2s, n);
    gather2_kernel<<<(n + 15) / 16, 256, 0, stream>>>(rowstart, eidx, dis, (const float2*)h2s,
                                                      b2, out, n);
}

// Round 9
// 174.542 us; speedup vs baseline: 1.1052x; 1.0052x over previous
//
#include <hip/hip_runtime.h>

// GCN 2-layer, CSR-by-dst gather formulation; h1s in bf16.
// R20 = EXACT R15 revert (BEST measured, 173.2us): bucket multisplit
//      CHUNK=8192 + fused csrBG (pairs staged to LDS once, LDS scatter,
//      coalesced eidx writeout). R19's cvec/Ws overlap edits measured +2.2us
//      -> reverted.
// Falsified alternatives (counters, keep for the record):
//   R14/R16: per-edge global atomics are toxic on MI355X (memory-side
//      write-through RMW ~32B/op + cross-XCD partial-line ping-pong).
//      eidx scatter: 106MB writes; deg hist: +50MB writes.
//   R17: CHUNK=2048 (more TLP) -> pairs runs too short, WRITE 35MB
//      amplification, bucketAC 46-48us. CHUNK=8192 is the sweet spot.
//   R18: coalesced-write chunks + csrBG run-gather -> 391 short scattered
//      run-reads per block, ~10/64 lanes active, lost ~20us.
//   R19: csrBG cvec-hoist + Ws-overlap: neutral-to-negative.
// gather1 frozen at its measured floor (~44us, latency-bound random h1s
// rows; R10 4-deep and R11 8-deep MLP both 43-45us at FETCH 81 MB).
// out = A_hat( relu( A_hat( [x|mean]@W1 ) + b1 ) @ W2 ) + b2
// Identity: [x|mean]@W1 = x@W1[:64] + c, c = mean@W1[64:].
// Pre-scaling: h1s[s] = dis[s]*(xW1+c)[s];  h2s[s] = dis[s]*(relu(.)@W2)[s].

#define NPB        256     // nodes per bucket
#define NPB_SHIFT  8
#define BKTS       512     // scan width (>= 391 buckets, pow2)
#define BKT_CAP    5120    // mean 4096 + 16 sigma
#define CHUNK      8192    // edges per bucketA block
#define EPT        16      // CHUNK / 512 threads
#define CS_BLK     128     // colsum+convert blocks prepended to bucketA grid
#define CUR_STRIDE 32      // ints per cursor slot (128-B line each)

using bf16x8 = __attribute__((ext_vector_type(8))) short;  // 8 bf16 (4 VGPRs)
using f32x4  = __attribute__((ext_vector_type(4))) float;

__device__ __forceinline__ unsigned short f2bf(float v) {
    unsigned u = __float_as_uint(v);
    u += 0x7FFFu + ((u >> 16) & 1u);   // round-to-nearest-even
    return (unsigned short)(u >> 16);
}
// two bf16 packed in a uint -> two floats (2 VALU)
__device__ __forceinline__ float bfu_lo(unsigned u) { return __uint_as_float(u << 16); }
__device__ __forceinline__ float bfu_hi(unsigned u) { return __uint_as_float(u & 0xFFFF0000u); }

// ---------- pass A: colsum+bf16cvt (0..127) + W^T->bf16 (128) + multi-split ----------
__global__ __launch_bounds__(512) void bucketAC_kernel(
        const int* __restrict__ src, const int* __restrict__ dst,
        int e, unsigned* __restrict__ pairs, int* __restrict__ cursor,
        const float* __restrict__ x, float* __restrict__ sums,
        const float* __restrict__ W1, unsigned short* __restrict__ wtg,
        unsigned short* __restrict__ xbf, int n) {
    int tid = threadIdx.x;
    if (blockIdx.x < CS_BLK) {
        // ---- colsum side-job + bf16 conversion of x ----
        __shared__ float4 s4[512];
        int cb = blockIdx.x;
        const float4* x4 = (const float4*)x;
        int total4 = n * 16;
        float4 acc = make_float4(0.f, 0.f, 0.f, 0.f);
        for (int i = cb * 512 + tid; i < total4; i += CS_BLK * 512) {
            float4 v = x4[i];
            acc.x += v.x; acc.y += v.y; acc.z += v.z; acc.w += v.w;
            ushort4 hv;
            hv.x = f2bf(v.x); hv.y = f2bf(v.y); hv.z = f2bf(v.z); hv.w = f2bf(v.w);
            *(ushort4*)&xbf[(size_t)i * 4] = hv;
        }
        s4[tid] = acc;
        __syncthreads();
        if (tid < 16) {
            float4 v = s4[tid];
            for (int k = 1; k < 32; ++k) {
                float4 w = s4[tid + 16 * k];
                v.x += w.x; v.y += w.y; v.z += w.z; v.w += w.w;
            }
            atomicAdd(&sums[tid * 4 + 0], v.x);
            atomicAdd(&sums[tid * 4 + 1], v.y);
            atomicAdd(&sums[tid * 4 + 2], v.z);
            atomicAdd(&sums[tid * 4 + 3], v.w);
        }
        return;
    }
    if (blockIdx.x == CS_BLK) {
        // ---- W transpose side-job: wtg[j*64+k] = bf16(W1[k*64+j]), k<64 ----
        for (int i = tid; i < 4096; i += 512) {
            int k = i >> 6, j = i & 63;
            wtg[j * 64 + k] = f2bf(W1[k * 64 + j]);
        }
        return;
    }
    // ---- bucket multi-split: packed 4-B records (src<<8 | dst&255) ----
    __shared__ int cnt[BKTS], gpos[BKTS];
    __shared__ int wsumA[8];
    __shared__ unsigned stage[CHUNK];
    __shared__ unsigned short bb[CHUNK];
    int chunkStart = (blockIdx.x - CS_BLK - 1) * CHUNK;
    int v = e - chunkStart;
    if (v > CHUNK) v = CHUNK;
    cnt[tid] = 0;
    __syncthreads();
    int myb[EPT], myoff[EPT];
    unsigned myp[EPT];
#pragma unroll
    for (int t = 0; t < EPT; ++t) {
        int i = chunkStart + t * 512 + tid;
        myb[t] = -1;
        if (i < e) {
            int s = src[i], d = dst[i];
            myb[t] = d >> NPB_SHIFT;
            myp[t] = ((unsigned)s << NPB_SHIFT) | (unsigned)(d & (NPB - 1));
            myoff[t] = atomicAdd(&cnt[myb[t]], 1);
        }
    }
    __syncthreads();
    // ---- shuffle-based inclusive scan over the 512 bucket counts ----
    int lane = tid & 63, wvi = tid >> 6;
    int myCnt = cnt[tid];
    int sv = myCnt;
#pragma unroll
    for (int off = 1; off < 64; off <<= 1) {
        int t = __shfl_up(sv, off, 64);
        if (lane >= off) sv += t;
    }
    if (lane == 63) wsumA[wvi] = sv;
    __syncthreads();
    int wbase = 0;
#pragma unroll
    for (int k = 0; k < 8; ++k) if (k < wvi) wbase += wsumA[k];
    int excl = sv + wbase - myCnt;
    if (myCnt > 0) {
        int gb = atomicAdd(&cursor[tid * CUR_STRIDE], myCnt);  // private line
        gpos[tid] = tid * BKT_CAP + gb - excl;
    }
    cnt[tid] = excl;  // reuse as stage base
    __syncthreads();
#pragma unroll
    for (int t = 0; t < EPT; ++t) {
        if (myb[t] >= 0) {
            int p = cnt[myb[t]] + myoff[t];
            stage[p] = myp[t];
            bb[p] = (unsigned short)myb[t];
        }
    }
    __syncthreads();
    for (int j = tid; j < v; j += 512) {
        int bk = bb[j];
        int wi = gpos[bk] + j;
        if (wi < (bk + 1) * BKT_CAP) pairs[wi] = stage[j];  // contiguous runs
    }
}

// ---------- pass B fused: CSR (LDS-staged hist+scan+fill) + cvec + MFMA gemm ----------
__global__ __launch_bounds__(512) void csrBG_kernel(
        const unsigned* __restrict__ pairs, const int* __restrict__ cursor,
        float* __restrict__ dis, int* __restrict__ rowstart,
        int* __restrict__ eidx, int n,
        const float* __restrict__ sums, const float* __restrict__ W1,
        const unsigned short* __restrict__ wtg, const unsigned short* __restrict__ xbf,
        unsigned short* __restrict__ h1s) {
    __shared__ int ldeg[NPB];       // later reused as float dis bits
    __shared__ int lcur[NPB];
    __shared__ int wred[8], wsum[8];
    __shared__ __align__(16) float cv[64];
    // union: phases 1-3 use pl (pairs local, 20KB) + el (eidx local, 20KB);
    // gemm phase reuses the same 40KB for Ws (9KB) + Xs (18.4KB).
    __shared__ __align__(16) char smem[BKT_CAP * 8];
    unsigned* pl = (unsigned*)smem;
    int* el = (int*)(smem + BKT_CAP * 4);
    unsigned short* Ws = (unsigned short*)smem;                    // 64*72
    unsigned short* Xs = (unsigned short*)(smem + 64 * 72 * 2);    // 2 tiles
    float* disl = (float*)ldeg;
    int b = blockIdx.x;
    int tid = threadIdx.x;
    int lane = tid & 63;
    int wvi = tid >> 6;
    int node0 = b << NPB_SHIFT;
    int nl = n - node0;
    if (nl > NPB) nl = NPB;
    int cnt_b = cursor[b * CUR_STRIDE];
    if (cnt_b > BKT_CAP) cnt_b = BKT_CAP;
    if (tid < NPB) ldeg[tid] = 0;
    // ---- ebase = sum of earlier buckets' counts, via shuffle reduction ----
    int c = (tid < b) ? cursor[tid * CUR_STRIDE] : 0;
#pragma unroll
    for (int off = 1; off < 64; off <<= 1) c += __shfl_xor(c, off, 64);
    if (lane == 0) wred[wvi] = c;
    __syncthreads();
    // ---- stage pairs to LDS + histogram in ONE pass (global read once) ----
    const unsigned* mp = pairs + (size_t)b * BKT_CAP;
    for (int i = tid; i < cnt_b; i += 512) {
        unsigned p = mp[i];
        pl[i] = p;
        atomicAdd(&ldeg[p & (NPB - 1)], 1);
    }
    int ebase = 0;
#pragma unroll
    for (int k = 0; k < 8; ++k) ebase += wred[k];
    __syncthreads();
    // ---- shuffle-based inclusive scan of the 256 degrees ----
    int mydeg = (tid < NPB) ? ldeg[tid] : 0;
    int sv = mydeg;
#pragma unroll
    for (int off = 1; off < 64; off <<= 1) {
        int t = __shfl_up(sv, off, 64);
        if (lane >= off) sv += t;
    }
    if (lane == 63) wsum[wvi] = sv;
    __syncthreads();
    int wbase = 0;
#pragma unroll
    for (int k = 0; k < 8; ++k) if (k < wvi) wbase += wsum[k];
    int excl = sv + wbase - mydeg;
    if (tid < NPB) {
        lcur[tid] = excl;
        if (tid < nl) rowstart[node0 + tid] = ebase + excl;
        // overwrite ldeg with dis bits; all ldeg reads are before the wsum barrier
        float dv = mydeg > 0 ? rsqrtf((float)mydeg) : 0.f;
        disl[tid] = dv;
        if (tid < nl) dis[node0 + tid] = dv;
    }
    if (tid == 0 && node0 + NPB >= n)          // last bucket: close the CSR
        rowstart[n] = ebase + cnt_b;
    __syncthreads();
    // ---- scatter LDS->LDS, then coalesced writeout ----
    for (int i = tid; i < cnt_b; i += 512) {
        unsigned p = pl[i];
        int pos = atomicAdd(&lcur[p & (NPB - 1)], 1);
        el[pos] = (int)(p >> NPB_SHIFT);
    }
    __syncthreads();
    for (int i = tid; i < cnt_b; i += 512)
        eidx[ebase + i] = el[i];               // fully coalesced
    // ---- cvec (redundant per block, trivial) ----
    if (tid < 64) {
        float inv_n = 1.0f / (float)n;
        float acc = 0.f;
        for (int k = 0; k < 64; ++k) acc += (sums[k] * inv_n) * W1[(64 + k) * 64 + tid];
        cv[tid] = acc;
    }
    __syncthreads();   // el/pl dead; smem becomes Ws/Xs
    // ---- stage W^T once ----
    for (int i = tid; i < 1024; i += 512) {
        int j = i >> 4, k4 = (i & 15) * 4;
        *(ushort4*)&Ws[j * 72 + k4] = *(const ushort4*)&wtg[j * 64 + k4];
    }
    // ---- gemm: 256 rows = 2 iters x 2 tiles x 64 rows ----
    int wv = wvi;               // 0..7
    int tile = wv >> 2;         // 0..1
    int w4 = wv & 3;            // wave within tile
    int l15 = lane & 15;
    int quad = lane >> 4;
#pragma unroll
    for (int it = 0; it < 2; ++it) {
        __syncthreads();
        // stage 128 rows (2 tiles) of pre-converted bf16 x
        for (int i = tid; i < 1024; i += 512) {
            int r = i >> 3, c8 = (i & 7) * 8;
            int gr = node0 + it * 128 + r;
            bf16x8 hv = {0, 0, 0, 0, 0, 0, 0, 0};
            if (gr < n) hv = *(const bf16x8*)&xbf[(size_t)gr * 64 + c8];
            *(bf16x8*)&Xs[((r >> 6) ? 64 * 72 : 0) + (r & 63) * 72 + c8] = hv;
        }
        __syncthreads();
        int xrow = w4 * 16 + l15;                    // row within tile
        f32x4 acc0 = {0.f, 0.f, 0.f, 0.f}, acc1 = acc0, acc2 = acc0, acc3 = acc0;
#pragma unroll
        for (int ks = 0; ks < 2; ++ks) {
            bf16x8 bfrag = *(const bf16x8*)&Xs[(tile ? 64 * 72 : 0) + xrow * 72 + ks * 32 + quad * 8];
            bf16x8 a0 = *(const bf16x8*)&Ws[(0 * 16 + l15) * 72 + ks * 32 + quad * 8];
            bf16x8 a1 = *(const bf16x8*)&Ws[(1 * 16 + l15) * 72 + ks * 32 + quad * 8];
            bf16x8 a2 = *(const bf16x8*)&Ws[(2 * 16 + l15) * 72 + ks * 32 + quad * 8];
            bf16x8 a3 = *(const bf16x8*)&Ws[(3 * 16 + l15) * 72 + ks * 32 + quad * 8];
            acc0 = __builtin_amdgcn_mfma_f32_16x16x32_bf16(a0, bfrag, acc0, 0, 0, 0);
            acc1 = __builtin_amdgcn_mfma_f32_16x16x32_bf16(a1, bfrag, acc1, 0, 0, 0);
            acc2 = __builtin_amdgcn_mfma_f32_16x16x32_bf16(a2, bfrag, acc2, 0, 0, 0);
            acc3 = __builtin_amdgcn_mfma_f32_16x16x32_bf16(a3, bfrag, acc3, 0, 0, 0);
        }
        int lrow = it * 128 + tile * 64 + xrow;      // row within bucket
        int grow = node0 + lrow;
        if (grow < n) {
            float dv = disl[lrow];
            const float4* c4 = (const float4*)cv;
            f32x4 accs[4] = {acc0, acc1, acc2, acc3};
#pragma unroll
            for (int t = 0; t < 4; ++t) {
                float4 cj = c4[t * 4 + quad];
                ushort4 hs;
                hs.x = f2bf((accs[t][0] + cj.x) * dv);
                hs.y = f2bf((accs[t][1] + cj.y) * dv);
                hs.z = f2bf((accs[t][2] + cj.z) * dv);
                hs.w = f2bf((accs[t][3] + cj.w) * dv);
                *(ushort4*)&h1s[(size_t)grow * 64 + t * 16 + quad * 4] = hs;
            }
        }
    }
}

// ---------- layer-1 gather: 32 lanes/edge (ushort2/lane), 8 loads in flight ----------
__global__ void gather1_kernel(const int* __restrict__ rowstart,
                               const int* __restrict__ eidx, const float* __restrict__ dis,
                               const unsigned short* __restrict__ h1s,
                               const float* __restrict__ b1, const float* __restrict__ W2,
                               float* __restrict__ h2s, int n) {
    int lane = threadIdx.x & 63;
    int node = blockIdx.x * 4 + (threadIdx.x >> 6);
    if (node >= n) return;
    int rs = rowstart[node];
    int re = rowstart[node + 1];
    int dn = re - rs;
    int m = dn < 64 ? dn : 64;
    int eHeld = (lane < m) ? eidx[rs + lane] : 0;  // one coalesced load for <=64 edges
    int sub = lane >> 5;        // edge subgroup 0..1
    int fp  = (lane & 31) * 2;  // feature pair base
    float ax = 0.f, ay = 0.f;
    int j = 0;
    for (; j + 16 <= m; j += 16) {        // 16 edges per iter, 8 loads in flight
        int s0 = __shfl(eHeld, j + 0 + sub, 64);
        int s1 = __shfl(eHeld, j + 2 + sub, 64);
        int s2 = __shfl(eHeld, j + 4 + sub, 64);
        int s3 = __shfl(eHeld, j + 6 + sub, 64);
        int s4 = __shfl(eHeld, j + 8 + sub, 64);
        int s5 = __shfl(eHeld, j + 10 + sub, 64);
        int s6 = __shfl(eHeld, j + 12 + sub, 64);
        int s7 = __shfl(eHeld, j + 14 + sub, 64);
        unsigned u0 = *(const unsigned*)&h1s[((size_t)s0 << 6) + fp];
        unsigned u1 = *(const unsigned*)&h1s[((size_t)s1 << 6) + fp];
        unsigned u2 = *(const unsigned*)&h1s[((size_t)s2 << 6) + fp];
        unsigned u3 = *(const unsigned*)&h1s[((size_t)s3 << 6) + fp];
        unsigned u4 = *(const unsigned*)&h1s[((size_t)s4 << 6) + fp];
        unsigned u5 = *(const unsigned*)&h1s[((size_t)s5 << 6) + fp];
        unsigned u6 = *(const unsigned*)&h1s[((size_t)s6 << 6) + fp];
        unsigned u7 = *(const unsigned*)&h1s[((size_t)s7 << 6) + fp];
        ax += (bfu_lo(u0) + bfu_lo(u1)) + (bfu_lo(u2) + bfu_lo(u3))
            + (bfu_lo(u4) + bfu_lo(u5)) + (bfu_lo(u6) + bfu_lo(u7));
        ay += (bfu_hi(u0) + bfu_hi(u1)) + (bfu_hi(u2) + bfu_hi(u3))
            + (bfu_hi(u4) + bfu_hi(u5)) + (bfu_hi(u6) + bfu_hi(u7));
    }
    for (; j + 8 <= m; j += 8) {          // 8-edge tail, 4 loads
        int s0 = __shfl(eHeld, j + 0 + sub, 64);
        int s1 = __shfl(eHeld, j + 2 + sub, 64);
        int s2 = __shfl(eHeld, j + 4 + sub, 64);
        int s3 = __shfl(eHeld, j + 6 + sub, 64);
        unsigned u0 = *(const unsigned*)&h1s[((size_t)s0 << 6) + fp];
        unsigned u1 = *(const unsigned*)&h1s[((size_t)s1 << 6) + fp];
        unsigned u2 = *(const unsigned*)&h1s[((size_t)s2 << 6) + fp];
        unsigned u3 = *(const unsigned*)&h1s[((size_t)s3 << 6) + fp];
        ax += (bfu_lo(u0) + bfu_lo(u1)) + (bfu_lo(u2) + bfu_lo(u3));
        ay += (bfu_hi(u0) + bfu_hi(u1)) + (bfu_hi(u2) + bfu_hi(u3));
    }
    for (; j + 4 <= m; j += 4) {          // 4-edge tail, 2 loads
        int s0 = __shfl(eHeld, j + 0 + sub, 64);
        int s1 = __shfl(eHeld, j + 2 + sub, 64);
        unsigned u0 = *(const unsigned*)&h1s[((size_t)s0 << 6) + fp];
        unsigned u1 = *(const unsigned*)&h1s[((size_t)s1 << 6) + fp];
        ax += bfu_lo(u0) + bfu_lo(u1);
        ay += bfu_hi(u0) + bfu_hi(u1);
    }
    for (; j < m; j += 2) {               // ragged tail (0..1 edges per sub)
        int jj = j + sub;
        int s = __shfl(eHeld, jj < m ? jj : 0, 64);
        if (jj < m) {
            unsigned u = *(const unsigned*)&h1s[((size_t)s << 6) + fp];
            ax += bfu_lo(u);
            ay += bfu_hi(u);
        }
    }
    for (int t = 64; t < dn; ++t) {       // deg > 64: astronomically rare here
        if (sub == 0) {
            int s = eidx[rs + t];
            unsigned u = *(const unsigned*)&h1s[((size_t)s << 6) + fp];
            ax += bfu_lo(u);
            ay += bfu_hi(u);
        }
    }
    // reduce across the 2 edge subgroups (both halves end with full sums)
    ax += __shfl_xor(ax, 32, 64);
    ay += __shfl_xor(ay, 32, 64);
    float di = dis[node];
    float2 bv = ((const float2*)b1)[lane & 31];
    float4 w = ((const float4*)W2)[lane & 31];   // W2[fp][0..1], W2[fp+1][0..1]
    float t0 = fmaxf(di * ax + bv.x, 0.f);
    float t1 = fmaxf(di * ay + bv.y, 0.f);
    float v0 = t0 * w.x + t1 * w.z;
    float v1 = t0 * w.y + t1 * w.w;
#pragma unroll
    for (int off = 1; off <= 16; off <<= 1) {   // sum the 32 feature classes
        v0 += __shfl_xor(v0, off, 64);
        v1 += __shfl_xor(v1, off, 64);
    }
    if (lane == 0) {
        h2s[(size_t)node * 2 + 0] = di * v0;
        h2s[(size_t)node * 2 + 1] = di * v1;
    }
}

// ---------- layer-2 gather: 16 lanes per node, one lane per edge ----------
__global__ void gather2_kernel(const int* __restrict__ rowstart,
                               const int* __restrict__ eidx, const float* __restrict__ dis,
                               const float2* __restrict__ h2s, const float* __restrict__ b2,
                               float2* __restrict__ out, int n) {
    int tid = threadIdx.x;
    int node = blockIdx.x * 16 + (tid >> 4);
    if (node >= n) return;
    int el = tid & 15;
    int rs = rowstart[node];
    int dn = rowstart[node + 1] - rs;
    float ax = 0.f, ay = 0.f;
    for (int t = el; t < dn; t += 16) {   // 16 edges in flight per node
        int s = eidx[rs + t];
        float2 h = h2s[s];
        ax += h.x;
        ay += h.y;
    }
#pragma unroll
    for (int off = 1; off <= 8; off <<= 1) {
        ax += __shfl_xor(ax, off, 64);
        ay += __shfl_xor(ay, off, 64);
    }
    if (el == 0) {
        float di = dis[node];
        out[node] = make_float2(di * ax + b2[0], di * ay + b2[1]);
    }
}

extern "C" void kernel_launch(void* const* d_in, const int* in_sizes, int n_in,
                              void* d_out, int out_size, void* d_ws, size_t ws_size,
                              hipStream_t stream) {
    const float* x  = (const float*)d_in[0];
    const int*   ei = (const int*)d_in[1];
    const float* W1 = (const float*)d_in[2];
    const float* b1 = (const float*)d_in[3];
    const float* W2 = (const float*)d_in[4];
    const float* b2 = (const float*)d_in[5];
    float2* out = (float2*)d_out;

    const int n = in_sizes[0] / 64;   // 100000
    const int e = in_sizes[1] / 2;    // 1600000
    const int* srcI = ei;
    const int* dstI = ei + e;
    const int nbkt = (n + NPB - 1) >> NPB_SHIFT;   // 391

    // workspace layout (256-B aligned segments); sums+cursor adjacent -> 1 memset
    char* p = (char*)d_ws;
    int* rowstart = (int*)p;    p += ((size_t)(n + 1) * 4 + 255) & ~255ull;
    float* dis    = (float*)p;  p += ((size_t)n * 4 + 255) & ~255ull;
    float* sums   = (float*)p;                  // 256 B
    int* cursor   = (int*)(p + 256);            // nbkt * 128-B padded slots
    size_t zsize  = 256 + (size_t)nbkt * CUR_STRIDE * 4;
    char* zbase   = p;          p += (zsize + 255) & ~255ull;
    unsigned short* wtg = (unsigned short*)p;  p += (4096 * 2 + 255) & ~255ull;
    unsigned short* xbf = (unsigned short*)p;  p += ((size_t)n * 64 * 2 + 255) & ~255ull;
    int* eidx     = (int*)p;    p += ((size_t)e * 4 + 255) & ~255ull;
    // keep pairs and h1s in SEPARATE regions (no union) - ws is large enough.
    unsigned* pairs = (unsigned*)p;  p += ((size_t)nbkt * BKT_CAP * 4 + 255) & ~255ull;
    unsigned short* h1s = (unsigned short*)p;  p += ((size_t)n * 64 * 2 + 255) & ~255ull;
    float* h2s    = (float*)p;

    hipMemsetAsync(zbase, 0, zsize, stream);

    const int nchunks = (e + CHUNK - 1) / CHUNK;           // 196

    bucketAC_kernel<<<CS_BLK + 1 + nchunks, 512, 0, stream>>>(srcI, dstI, e, pairs, cursor,
                                                              x, sums, W1, wtg, xbf, n);
    csrBG_kernel<<<nbkt, 512, 0, stream>>>(pairs, cursor, dis, rowstart, eidx, n,
                                           sums, W1, wtg, xbf, h1s);
    gather1_kernel<<<(n + 3) / 4, 256, 0, stream>>>(rowstart, eidx, dis, h1s, b1, W2, h2s, n);
    gather2_kernel<<<(n + 15) / 16, 256, 0, stream>>>(rowstart, eidx, dis, (const float2*)h2s,
                                                      b2, out, n);
}